// Round 6
// baseline (218.230 us; speedup 1.0000x reference)
//
#include <hip/hip_runtime.h>

// GCN: 3 layers, h = relu(h + GCNConv(h)), fixed graph, f32 in/out.
// g and hb (bf16) split into two 4MB feature-half planes so the gather's
// random row reads are per-XCD L2-resident (one pass per plane).

typedef __attribute__((ext_vector_type(8))) short short8;   // 8 bf16 = 4 VGPR
typedef __attribute__((ext_vector_type(4))) float f32x4;
typedef __attribute__((ext_vector_type(2))) float f32x2;    // native vec for nt-store

__device__ inline ushort f2bf(float f) {           // RNE f32 -> bf16
    union { float f; unsigned u; } v; v.f = f;
    unsigned u = v.u;
    return (ushort)((u + 0x7fffu + ((u >> 16) & 1u)) >> 16);
}
__device__ inline float2 bf2f(unsigned u) {        // two packed bf16 -> float2
    union { unsigned i; float f; } a, b;
    a.i = u << 16;
    b.i = u & 0xffff0000u;
    return make_float2(a.f, b.f);
}

// ---------------- degree ----------------
__global__ void k_deg(const int* __restrict__ col, int* __restrict__ deg, int E) {
    int i = blockIdx.x * blockDim.x + threadIdx.x;
    if (i < E) atomicAdd(&deg[col[i]], 1);
}

// ---------------- hierarchical exclusive scan ----------------
__global__ __launch_bounds__(256) void k_scan1(const int* __restrict__ deg,
                                               int* __restrict__ offs,
                                               int* __restrict__ bsum, int n) {
    __shared__ int sm[256];
    int t = threadIdx.x, i = blockIdx.x * 256 + t;
    int v = (i < n) ? deg[i] : 0;
    sm[t] = v;
    __syncthreads();
    for (int off = 1; off < 256; off <<= 1) {
        int u = (t >= off) ? sm[t - off] : 0;
        __syncthreads();
        sm[t] += u;
        __syncthreads();
    }
    if (i < n) offs[i] = sm[t] - v;
    if (t == 255) bsum[blockIdx.x] = sm[255];
}

__global__ __launch_bounds__(128) void k_scan2(int* __restrict__ bsum, int nb) {
    __shared__ int sm[128];
    int t = threadIdx.x;
    int v = (t < nb) ? bsum[t] : 0;
    sm[t] = v;
    __syncthreads();
    for (int off = 1; off < 128; off <<= 1) {
        int u = (t >= off) ? sm[t - off] : 0;
        __syncthreads();
        sm[t] += u;
        __syncthreads();
    }
    if (t < nb) bsum[t] = sm[t] - v;
}

// offs final; cnt = copy (CSR cursor); dis = rsqrt(deg+1)
__global__ __launch_bounds__(256) void k_scan3(int* __restrict__ offs,
                                               const int* __restrict__ bsum,
                                               const int* __restrict__ deg,
                                               int* __restrict__ cnt,
                                               float* __restrict__ dis,
                                               int n, int E) {
    int i = blockIdx.x * 256 + threadIdx.x;
    if (i < n) {
        int o = offs[i] + bsum[blockIdx.x];
        offs[i] = o;
        cnt[i] = o;
        dis[i] = rsqrtf((float)(deg[i] + 1));
    }
    if (i == 0) offs[n] = E;
}

// ---------------- CSR build (ushort indices; order nondeterministic) ----------
__global__ void k_csr(const int* __restrict__ row, const int* __restrict__ col,
                      int* __restrict__ cnt, ushort* __restrict__ csru, int E) {
    int i = blockIdx.x * blockDim.x + threadIdx.x;
    if (i < E) {
        int c = col[i];
        int p = atomicAdd(&cnt[c], 1);
        csru[p] = (ushort)row[i];
    }
}

// ---------------- x (f32) -> hb planes; zero the pad rows of g planes --------
__global__ void k_cvt(const float* __restrict__ x,
                      unsigned* __restrict__ hb0, unsigned* __restrict__ hb1,
                      unsigned* __restrict__ g0, unsigned* __restrict__ g1,
                      int n) {
    int i = blockIdx.x * blockDim.x + threadIdx.x;
    int m = n * 64;
    if (i < m) {
        float2 v = ((const float2*)x)[i];
        unsigned pk = ((unsigned)f2bf(v.y) << 16) | f2bf(v.x);
        int node = i >> 6, d = i & 63;
        (d < 32 ? hb0 : hb1)[node * 32 + (d & 31)] = pk;
    }
    if (i < 32) {            // pad row n = zeros (gather tail reads it)
        g0[(size_t)n * 32 + i] = 0;
        g1[(size_t)n * 32 + i] = 0;
    }
}

// ---------------- MFMA GEMM: g planes = bf16((hb @ W) * dis[row]) ------------
// In-kernel W transpose to swizzled LDS (saves the k_wt launch).
__global__ __launch_bounds__(256) void k_gemm(const unsigned* __restrict__ hb0,
                                              const unsigned* __restrict__ hb1,
                                              const float* __restrict__ W,
                                              const float* __restrict__ dis,
                                              ushort* __restrict__ g0,
                                              ushort* __restrict__ g1, int n) {
    __shared__ unsigned Wl[128][64];   // [n][k-pair] bf16x2, XOR-swizzled, 32KB
    int tid = threadIdx.x;
    {
        int nn = tid & 127, hf = tid >> 7;
        for (int q = 0; q < 32; ++q) {
            int k2 = hf * 32 + q;
            float lo = W[(size_t)(2 * k2) * 128 + nn];
            float hi = W[(size_t)(2 * k2 + 1) * 128 + nn];
            Wl[nn][k2 ^ ((nn & 7) << 2)] = ((unsigned)f2bf(hi) << 16) | f2bf(lo);
        }
    }
    __syncthreads();

    int w = tid >> 6, l = tid & 63;
    int rb = blockIdx.x * 64 + w * 16;
    int c = l & 15, q = l >> 4;

    // A fragments from hb planes: row rb+c; chunk(ks,q) = dwords ks*16+q*4
    const short8* r0 = (const short8*)(hb0 + (size_t)(rb + c) * 32);
    const short8* r1 = (const short8*)(hb1 + (size_t)(rb + c) * 32);
    short8 a0 = __builtin_nontemporal_load(&r0[q]);
    short8 a1 = __builtin_nontemporal_load(&r0[4 + q]);
    short8 a2 = __builtin_nontemporal_load(&r1[q]);
    short8 a3 = __builtin_nontemporal_load(&r1[4 + q]);

    f32x4 acc[8] = {};
#pragma unroll
    for (int nf = 0; nf < 8; ++nf) {
        const unsigned* wr = &Wl[nf * 16 + c][0];
        int s = (c & 7) << 2;            // (nn&7)<<2, nn = nf*16+c
        int b = q * 4;
        short8 b0 = *(const short8*)(wr + ((b +  0) ^ s));
        short8 b1 = *(const short8*)(wr + ((b + 16) ^ s));
        short8 b2 = *(const short8*)(wr + ((b + 32) ^ s));
        short8 b3 = *(const short8*)(wr + ((b + 48) ^ s));
        acc[nf] = __builtin_amdgcn_mfma_f32_16x16x32_bf16(a0, b0, acc[nf], 0, 0, 0);
        acc[nf] = __builtin_amdgcn_mfma_f32_16x16x32_bf16(a1, b1, acc[nf], 0, 0, 0);
        acc[nf] = __builtin_amdgcn_mfma_f32_16x16x32_bf16(a2, b2, acc[nf], 0, 0, 0);
        acc[nf] = __builtin_amdgcn_mfma_f32_16x16x32_bf16(a3, b3, acc[nf], 0, 0, 0);
    }

    // C/D: col = nf*16+c, row = rb + q*4 + j; plane = nf>>2
    float d0 = dis[rb + q * 4 + 0], d1 = dis[rb + q * 4 + 1];
    float d2 = dis[rb + q * 4 + 2], d3 = dis[rb + q * 4 + 3];
#pragma unroll
    for (int nf = 0; nf < 8; ++nf) {
        ushort* gp = (nf < 4) ? g0 : g1;
        int cp = (nf & 3) * 16 + c;
        gp[(size_t)(rb + q * 4 + 0) * 64 + cp] = f2bf(acc[nf][0] * d0);
        gp[(size_t)(rb + q * 4 + 1) * 64 + cp] = f2bf(acc[nf][1] * d1);
        gp[(size_t)(rb + q * 4 + 2) * 64 + cp] = f2bf(acc[nf][2] * d2);
        gp[(size_t)(rb + q * 4 + 3) * 64 + cp] = f2bf(acc[nf][3] * d3);
    }
}

// ---------------- gather pass over one 4MB plane ----------------
// One wave per node; lanes split 2x32: half h processes neighbors 2t+h.
// Per neighbor: 1 dword (2 bf16) per lane from the L2-resident plane.
__global__ __launch_bounds__(256) void k_gather(const unsigned* __restrict__ gp,
                                                unsigned* __restrict__ hbp,
                                                const float* __restrict__ dis,
                                                const float2* __restrict__ biasp,
                                                const int* __restrict__ offs,
                                                const ushort* __restrict__ csru,
                                                float* __restrict__ outp,
                                                int n, int last) {
    int wid = threadIdx.x >> 6, lane = threadIdx.x & 63;
    int node = blockIdx.x * 4 + wid;
    if (node >= n) return;
    int half = lane >> 5, fl = lane & 31;
    int fo = fl * 4;
    const char* gpb = (const char*)gp;

    // self-loop: lanes 0-31 read g[node], lanes 32-63 read zero pad row
    float2 acc = bf2f(*(const unsigned*)(gpb + ((half ? n : node) << 7) + fo));

    int s = offs[node];
    int deg = offs[node + 1] - s;
    for (int j0 = 0; j0 < deg; j0 += 64) {
        int rem = deg - j0;
        int m = rem < 64 ? rem : 64;
        int idx = (lane < m) ? (int)__builtin_nontemporal_load(&csru[s + j0 + lane]) : n;
        int offv = idx << 7;                 // byte offset of plane row
        int mc = (m + 1) & ~1;
        int t = 0;
        for (; t + 8 <= mc; t += 8) {
            int o0 = __shfl(offv, t + 0 + half, 64);
            int o1 = __shfl(offv, t + 2 + half, 64);
            int o2 = __shfl(offv, t + 4 + half, 64);
            int o3 = __shfl(offv, t + 6 + half, 64);
            unsigned v0 = *(const unsigned*)(gpb + o0 + fo);
            unsigned v1 = *(const unsigned*)(gpb + o1 + fo);
            unsigned v2 = *(const unsigned*)(gpb + o2 + fo);
            unsigned v3 = *(const unsigned*)(gpb + o3 + fo);
            float2 f0 = bf2f(v0), f1 = bf2f(v1), f2 = bf2f(v2), f3 = bf2f(v3);
            acc.x += (f0.x + f1.x) + (f2.x + f3.x);
            acc.y += (f0.y + f1.y) + (f2.y + f3.y);
        }
        for (; t < mc; t += 2) {
            int o = __shfl(offv, t + half, 64);
            float2 f = bf2f(*(const unsigned*)(gpb + o + fo));
            acc.x += f.x; acc.y += f.y;
        }
    }
    acc.x += __shfl_xor(acc.x, 32, 64);
    acc.y += __shfl_xor(acc.y, 32, 64);

    if (half == 0) {
        float d = dis[node];
        float2 bv = biasp[fl];
        float2 hv = bf2f(__builtin_nontemporal_load(&hbp[node * 32 + fl]));
        float ox = fmaxf(hv.x + acc.x * d + bv.x, 0.f);
        float oy = fmaxf(hv.y + acc.y * d + bv.y, 0.f);
        if (last) {
            f32x2 o2v = { ox, oy };
            __builtin_nontemporal_store(o2v, (f32x2*)&outp[(size_t)node * 128 + fl * 2]);
        } else {
            unsigned pk = ((unsigned)f2bf(oy) << 16) | f2bf(ox);
            __builtin_nontemporal_store(pk, &hbp[node * 32 + fl]);
        }
    }
}

static inline size_t al256(size_t x) { return (x + 255) & ~(size_t)255; }

extern "C" void kernel_launch(void* const* d_in, const int* in_sizes, int n_in,
                              void* d_out, int out_size, void* d_ws, size_t ws_size,
                              hipStream_t stream) {
    const float* x  = (const float*)d_in[0];
    const int*   ei = (const int*)d_in[1];
    const float* Ws = (const float*)d_in[2];
    const float* bs = (const float*)d_in[3];
    int n  = in_sizes[0] / 128;          // 32768 nodes
    int E  = in_sizes[1] / 2;            // 524288 edges
    int NL = in_sizes[2] / (128 * 128);  // 3 layers
    const int* rowp = ei;
    const int* colp = ei + E;

    char* ws = (char*)d_ws;
    size_t plane = al256((size_t)(n + 1) * 128);     // (n+1) rows x 128B
    unsigned* g0  = (unsigned*)ws;
    unsigned* g1  = (unsigned*)(ws + plane);
    unsigned* hb0 = (unsigned*)(ws + 2 * plane);
    unsigned* hb1 = (unsigned*)(ws + 3 * plane);
    char* p = ws + 4 * plane;
    float* dis  = (float*)p;               p += al256((size_t)n * 4);
    int*   deg  = (int*)p;                 p += al256((size_t)n * 4);
    int*   offs = (int*)p;                 p += al256((size_t)(n + 1) * 4);
    int*   cnt  = (int*)p;                 p += al256((size_t)n * 4);
    int*   bsum = (int*)p;                 p += 512;
    ushort* csru = (ushort*)p;

    int nb = (n + 255) / 256;            // 128 scan blocks

    (void)hipMemsetAsync(deg, 0, (size_t)n * 4, stream);
    k_deg<<<(E + 255) / 256, 256, 0, stream>>>(colp, deg, E);
    k_scan1<<<nb, 256, 0, stream>>>(deg, offs, bsum, n);
    k_scan2<<<1, 128, 0, stream>>>(bsum, nb);
    k_scan3<<<nb, 256, 0, stream>>>(offs, bsum, deg, cnt, dis, n, E);
    k_csr<<<(E + 255) / 256, 256, 0, stream>>>(rowp, colp, cnt, csru, E);
    k_cvt<<<(n * 64 + 255) / 256, 256, 0, stream>>>(x, hb0, hb1, g0, g1, n);

    for (int l = 0; l < NL; ++l) {
        int last = (l + 1 == NL);
        k_gemm<<<n / 64, 256, 0, stream>>>(hb0, hb1, Ws + (size_t)l * 128 * 128,
                                           dis, (ushort*)g0, (ushort*)g1, n);
        k_gather<<<(n + 3) / 4, 256, 0, stream>>>(g0, hb0, dis,
                                                  (const float2*)(bs + (size_t)l * 128),
                                                  offs, csru,
                                                  (float*)d_out, n, last);
        k_gather<<<(n + 3) / 4, 256, 0, stream>>>(g1, hb1, dis,
                                                  (const float2*)(bs + (size_t)l * 128) + 32,
                                                  offs, csru,
                                                  (float*)d_out + 64, n, last);
    }
}

// Round 7
// 165.003 us; speedup vs baseline: 1.3226x; 1.3226x over previous
//
#include <hip/hip_runtime.h>

// GCN: 3 layers, h = relu(h + GCNConv(h)), fixed graph, f32 in/out.
// Single bf16 g plane (8MB, L3-resident); gather = wave/node, 16-deep MLP,
// branch-free tail via zero pad row. h carried as bf16 (hb) between layers.

typedef __attribute__((ext_vector_type(8))) short short8;   // 8 bf16 = 4 VGPR
typedef __attribute__((ext_vector_type(4))) float f32x4;
typedef __attribute__((ext_vector_type(2))) float f32x2;

__device__ inline ushort f2bf(float f) {           // RNE f32 -> bf16
    union { float f; unsigned u; } v; v.f = f;
    unsigned u = v.u;
    return (ushort)((u + 0x7fffu + ((u >> 16) & 1u)) >> 16);
}
__device__ inline float2 bf2f(unsigned u) {        // two packed bf16 -> float2
    union { unsigned i; float f; } a, b;
    a.i = u << 16;
    b.i = u & 0xffff0000u;
    return make_float2(a.f, b.f);
}

// ---------------- degree ----------------
__global__ void k_deg(const int* __restrict__ col, int* __restrict__ deg, int E) {
    int i = blockIdx.x * blockDim.x + threadIdx.x;
    if (i < E) atomicAdd(&deg[col[i]], 1);
}

// ---------------- hierarchical exclusive scan ----------------
__global__ __launch_bounds__(256) void k_scan1(const int* __restrict__ deg,
                                               int* __restrict__ offs,
                                               int* __restrict__ bsum, int n) {
    __shared__ int sm[256];
    int t = threadIdx.x, i = blockIdx.x * 256 + t;
    int v = (i < n) ? deg[i] : 0;
    sm[t] = v;
    __syncthreads();
    for (int off = 1; off < 256; off <<= 1) {
        int u = (t >= off) ? sm[t - off] : 0;
        __syncthreads();
        sm[t] += u;
        __syncthreads();
    }
    if (i < n) offs[i] = sm[t] - v;
    if (t == 255) bsum[blockIdx.x] = sm[255];
}

__global__ __launch_bounds__(128) void k_scan2(int* __restrict__ bsum, int nb) {
    __shared__ int sm[128];
    int t = threadIdx.x;
    int v = (t < nb) ? bsum[t] : 0;
    sm[t] = v;
    __syncthreads();
    for (int off = 1; off < 128; off <<= 1) {
        int u = (t >= off) ? sm[t - off] : 0;
        __syncthreads();
        sm[t] += u;
        __syncthreads();
    }
    if (t < nb) bsum[t] = sm[t] - v;
}

// offs final; cnt = copy (CSR cursor); dis = rsqrt(deg+1)
__global__ __launch_bounds__(256) void k_scan3(int* __restrict__ offs,
                                               const int* __restrict__ bsum,
                                               const int* __restrict__ deg,
                                               int* __restrict__ cnt,
                                               float* __restrict__ dis,
                                               int n, int E) {
    int i = blockIdx.x * 256 + threadIdx.x;
    if (i < n) {
        int o = offs[i] + bsum[blockIdx.x];
        offs[i] = o;
        cnt[i] = o;
        dis[i] = rsqrtf((float)(deg[i] + 1));
    }
    if (i == 0) offs[n] = E;
}

// ---------------- CSR build (ushort indices; order nondeterministic) ----------
__global__ void k_csr(const int* __restrict__ row, const int* __restrict__ col,
                      int* __restrict__ cnt, ushort* __restrict__ csru, int E) {
    int i = blockIdx.x * blockDim.x + threadIdx.x;
    if (i < E) {
        int c = col[i];
        int p = atomicAdd(&cnt[c], 1);
        csru[p] = (ushort)row[i];
    }
}

// ---------------- x (f32) -> hb bf16; zero the pad row of g ----------
__global__ void k_cvt(const float* __restrict__ x, unsigned* __restrict__ hb,
                      unsigned* __restrict__ g, int n) {
    int i = blockIdx.x * blockDim.x + threadIdx.x;
    if (i < n * 64) {
        float2 v = ((const float2*)x)[i];
        hb[i] = ((unsigned)f2bf(v.y) << 16) | f2bf(v.x);
    }
    if (i < 64) g[(size_t)n * 64 + i] = 0;   // pad row (branch-free gather tail)
}

// ---------------- MFMA GEMM: g = bf16((hb @ W) * dis[row]) ------------
// In-kernel W transpose to XOR-swizzled LDS.
__global__ __launch_bounds__(256) void k_gemm(const unsigned* __restrict__ hb,
                                              const float* __restrict__ W,
                                              const float* __restrict__ dis,
                                              ushort* __restrict__ g, int n) {
    __shared__ unsigned Wl[128][64];   // [n][k-pair] bf16x2, XOR-swizzled, 32KB
    int tid = threadIdx.x;
    {
        int nn = tid & 127, hf = tid >> 7;
        for (int q = 0; q < 32; ++q) {
            int k2 = hf * 32 + q;
            float lo = W[(size_t)(2 * k2) * 128 + nn];
            float hi = W[(size_t)(2 * k2 + 1) * 128 + nn];
            Wl[nn][k2 ^ ((nn & 7) << 2)] = ((unsigned)f2bf(hi) << 16) | f2bf(lo);
        }
    }
    __syncthreads();

    int w = tid >> 6, l = tid & 63;
    int rb = blockIdx.x * 64 + w * 16;
    int c = l & 15, q = l >> 4;

    // A fragments: lane row rb+c, chunk ks -> k = ks*32 + q*8 .. +7
    const short8* arow = (const short8*)(hb + (size_t)(rb + c) * 64);
    short8 a0 = arow[q], a1 = arow[4 + q], a2 = arow[8 + q], a3 = arow[12 + q];

    f32x4 acc[8] = {};
#pragma unroll
    for (int nf = 0; nf < 8; ++nf) {
        const unsigned* wr = &Wl[nf * 16 + c][0];
        int s = (c & 7) << 2;
        int b = q * 4;
        short8 b0 = *(const short8*)(wr + ((b +  0) ^ s));
        short8 b1 = *(const short8*)(wr + ((b + 16) ^ s));
        short8 b2 = *(const short8*)(wr + ((b + 32) ^ s));
        short8 b3 = *(const short8*)(wr + ((b + 48) ^ s));
        acc[nf] = __builtin_amdgcn_mfma_f32_16x16x32_bf16(a0, b0, acc[nf], 0, 0, 0);
        acc[nf] = __builtin_amdgcn_mfma_f32_16x16x32_bf16(a1, b1, acc[nf], 0, 0, 0);
        acc[nf] = __builtin_amdgcn_mfma_f32_16x16x32_bf16(a2, b2, acc[nf], 0, 0, 0);
        acc[nf] = __builtin_amdgcn_mfma_f32_16x16x32_bf16(a3, b3, acc[nf], 0, 0, 0);
    }

    // C/D: col = nf*16+c, row = rb + q*4 + j   [verified mapping]
    float d0 = dis[rb + q * 4 + 0], d1 = dis[rb + q * 4 + 1];
    float d2 = dis[rb + q * 4 + 2], d3 = dis[rb + q * 4 + 3];
#pragma unroll
    for (int nf = 0; nf < 8; ++nf) {
        int gc = nf * 16 + c;
        g[(size_t)(rb + q * 4 + 0) * 128 + gc] = f2bf(acc[nf][0] * d0);
        g[(size_t)(rb + q * 4 + 1) * 128 + gc] = f2bf(acc[nf][1] * d1);
        g[(size_t)(rb + q * 4 + 2) * 128 + gc] = f2bf(acc[nf][2] * d2);
        g[(size_t)(rb + q * 4 + 3) * 128 + gc] = f2bf(acc[nf][3] * d3);
    }
}

// ---------------- gather: out = relu(hb + dis[c]*(g[c] + sum g[nbr]) + b) ------
// Wave per node, 1 dword (2 bf16) per lane per neighbor (256B/row),
// 16 independent row-loads in flight, tail padded to 16 via zero row n.
__global__ __launch_bounds__(256) void k_gather(const unsigned* __restrict__ g,
                                                unsigned* __restrict__ hb,
                                                const float* __restrict__ dis,
                                                const float2* __restrict__ bias2,
                                                const int* __restrict__ offs,
                                                const ushort* __restrict__ csru,
                                                float* __restrict__ outp,
                                                int n, int last) {
    int wid = threadIdx.x >> 6, lane = threadIdx.x & 63;
    int node = blockIdx.x * 4 + wid;
    if (node >= n) return;
    size_t nb = (size_t)node * 64 + lane;
    float2 acc = bf2f(g[nb]);                  // self-loop term
    int s = offs[node];
    int deg = offs[node + 1] - s;
    for (int j0 = 0; j0 < deg; j0 += 64) {
        int rem = deg - j0;
        int m = rem < 64 ? rem : 64;
        int idx = (lane < m) ? (int)__builtin_nontemporal_load(&csru[s + j0 + lane]) : n;
        int mc = (m + 15) & ~15;               // pad chunk: idx=n reads zero row
        for (int t = 0; t < mc; t += 16) {
            unsigned v[16];
#pragma unroll
            for (int u = 0; u < 16; ++u)
                v[u] = g[(size_t)__shfl(idx, t + u, 64) * 64 + lane];
            float2 p0, p1;
#define ACC2(A, B, O)  p0 = bf2f(v[A]); p1 = bf2f(v[B]); \
                       O.x = p0.x + p1.x; O.y = p0.y + p1.y;
            float2 s0, s1, s2, s3, s4, s5, s6, s7;
            ACC2(0, 1, s0)  ACC2(2, 3, s1)  ACC2(4, 5, s2)  ACC2(6, 7, s3)
            ACC2(8, 9, s4)  ACC2(10, 11, s5) ACC2(12, 13, s6) ACC2(14, 15, s7)
#undef ACC2
            s0.x += s1.x; s2.x += s3.x; s4.x += s5.x; s6.x += s7.x;
            s0.y += s1.y; s2.y += s3.y; s4.y += s5.y; s6.y += s7.y;
            acc.x += (s0.x + s2.x) + (s4.x + s6.x);
            acc.y += (s0.y + s2.y) + (s4.y + s6.y);
        }
    }
    float d = dis[node];
    float2 bv = bias2[lane];
    float2 hv = bf2f(hb[nb]);
    float ox = fmaxf(hv.x + acc.x * d + bv.x, 0.f);
    float oy = fmaxf(hv.y + acc.y * d + bv.y, 0.f);
    if (last) {
        f32x2 o = { ox, oy };
        __builtin_nontemporal_store(o, (f32x2*)&outp[(size_t)node * 128 + lane * 2]);
    } else {
        hb[nb] = ((unsigned)f2bf(oy) << 16) | f2bf(ox);
    }
}

static inline size_t al256(size_t x) { return (x + 255) & ~(size_t)255; }

extern "C" void kernel_launch(void* const* d_in, const int* in_sizes, int n_in,
                              void* d_out, int out_size, void* d_ws, size_t ws_size,
                              hipStream_t stream) {
    const float* x  = (const float*)d_in[0];
    const int*   ei = (const int*)d_in[1];
    const float* Ws = (const float*)d_in[2];
    const float* bs = (const float*)d_in[3];
    int n  = in_sizes[0] / 128;          // 32768 nodes
    int E  = in_sizes[1] / 2;            // 524288 edges
    int NL = in_sizes[2] / (128 * 128);  // 3 layers
    const int* rowp = ei;
    const int* colp = ei + E;

    char* ws = (char*)d_ws;
    size_t plane = al256((size_t)(n + 1) * 256);     // (n+1) rows x 256B
    unsigned* g  = (unsigned*)ws;
    unsigned* hb = (unsigned*)(ws + plane);
    char* p = ws + 2 * plane;
    float* dis  = (float*)p;               p += al256((size_t)n * 4);
    int*   deg  = (int*)p;                 p += al256((size_t)n * 4);
    int*   offs = (int*)p;                 p += al256((size_t)(n + 1) * 4);
    int*   cnt  = (int*)p;                 p += al256((size_t)n * 4);
    int*   bsum = (int*)p;                 p += 512;
    ushort* csru = (ushort*)p;

    int nb = (n + 255) / 256;            // 128 scan blocks

    (void)hipMemsetAsync(deg, 0, (size_t)n * 4, stream);
    k_deg<<<(E + 255) / 256, 256, 0, stream>>>(colp, deg, E);
    k_scan1<<<nb, 256, 0, stream>>>(deg, offs, bsum, n);
    k_scan2<<<1, 128, 0, stream>>>(bsum, nb);
    k_scan3<<<nb, 256, 0, stream>>>(offs, bsum, deg, cnt, dis, n, E);
    k_csr<<<(E + 255) / 256, 256, 0, stream>>>(rowp, colp, cnt, csru, E);
    k_cvt<<<(n * 64 + 255) / 256, 256, 0, stream>>>(x, hb, g, n);

    for (int l = 0; l < NL; ++l) {
        int last = (l + 1 == NL);
        k_gemm<<<n / 64, 256, 0, stream>>>(hb, Ws + (size_t)l * 128 * 128,
                                           dis, (ushort*)g, n);
        k_gather<<<(n + 3) / 4, 256, 0, stream>>>(g, hb, dis,
                                                  (const float2*)(bs + (size_t)l * 128),
                                                  offs, csru, (float*)d_out, n, last);
    }
}